// Round 6
// baseline (2049.239 us; speedup 1.0000x reference)
//
#include <hip/hip_runtime.h>

typedef unsigned short u16;
typedef short short8 __attribute__((ext_vector_type(8)));
typedef float f32x4 __attribute__((ext_vector_type(4)));
typedef float float4v __attribute__((ext_vector_type(4)));
typedef u16 u16x4 __attribute__((ext_vector_type(4)));
typedef unsigned long long u64;

// ======== DIAGNOSTIC ROUND: grid-replicated idempotent dispatches ========
// Each kernel runs REP_* identical copies (blockIdx.y/z replication) writing
// identical values to identical addresses so every dispatch exceeds the
// harness poison-fill duration (~150us) and surfaces in rocprof top-5.
#define REP_PREP 16
#define REP_QKV  8
#define REP_ATTN 12
#define REP_OPRJ 16

// ---------- helpers ----------
__device__ __forceinline__ u16 f2bf(float f) {
  union { float f; unsigned u; } v; v.f = f;
  unsigned r = v.u + 0x7FFFu + ((v.u >> 16) & 1u);   // round-to-nearest-even
  return (u16)(r >> 16);
}

__device__ __forceinline__ unsigned cvtpk(float lo, float hi) {
  unsigned r;
  asm("v_cvt_pk_bf16_f32 %0, %1, %2" : "=v"(r) : "v"(lo), "v"(hi));
  return r;
}

__device__ __forceinline__ void gload16(const u16* g, u16* l) {
  __builtin_amdgcn_global_load_lds(
      (const __attribute__((address_space(1))) void*)g,
      (__attribute__((address_space(3))) void*)l, 16, 0, 0);
}

// ---------- merged prep: maskbits (0..4095), xcvt (4096..8191), wcvt (8192..12287) ----------
__global__ __launch_bounds__(256)
void prep_kernel(const void* __restrict__ mask, u64* __restrict__ bits,
                 const float* __restrict__ x, u16* __restrict__ xb,
                 const float* __restrict__ W0, const float* __restrict__ W1,
                 const float* __restrict__ W2, const float* __restrict__ W3,
                 u16* __restrict__ Wt) {
  __shared__ float t[32][33];
  __shared__ int sf;
  const int bid = blockIdx.x;
  if (bid < 4096) {
    // ---- maskbits with self-detected dtype (fmt: 0=u8, 1=i32, 2=f32, 3=i64) ----
    if (threadIdx.x == 0) sf = 0;
    __syncthreads();
    {
      uint4 v = ((const uint4*)mask)[threadIdx.x];
      unsigned xs[4] = {v.x, v.y, v.z, v.w};
      int f = 0;
#pragma unroll
      for (int d = 0; d < 4; ++d) {
        unsigned u = xs[d];
        if (u == 0x3F800000u) f |= 1;
        if (u & 0xFFFFFF00u) f |= 2;
        if ((d & 1) && u) f |= 4;
      }
      if (f) atomicOr(&sf, f);
    }
    __syncthreads();
    const int fl = sf;
    const int fmt = (fl & 1) ? 2 : ((fl & 2) ? 0 : ((fl & 4) ? 1 : 3));

    const int wi = bid * 256 + threadIdx.x;  // 1M words
    u64 b = 0;
    if (fmt == 0) {
      const uint4* mp = (const uint4*)mask + (size_t)wi * 4;
#pragma unroll
      for (int i = 0; i < 4; ++i) {
        uint4 v = mp[i];
        unsigned xw[4] = {v.x, v.y, v.z, v.w};
#pragma unroll
        for (int d = 0; d < 4; ++d)
#pragma unroll
          for (int by = 0; by < 4; ++by)
            if (xw[d] & (0xFFu << (by * 8))) b |= 1ULL << (i * 16 + d * 4 + by);
      }
    } else if (fmt != 3) {
      const uint4* mp = (const uint4*)mask + (size_t)wi * 16;
#pragma unroll
      for (int i = 0; i < 16; ++i) {
        uint4 v = mp[i];
        if (v.x) b |= 1ULL << (i * 4 + 0);
        if (v.y) b |= 1ULL << (i * 4 + 1);
        if (v.z) b |= 1ULL << (i * 4 + 2);
        if (v.w) b |= 1ULL << (i * 4 + 3);
      }
    } else {
      const uint4* mp = (const uint4*)mask + (size_t)wi * 32;
#pragma unroll
      for (int i = 0; i < 32; ++i) {
        uint4 v = mp[i];
        if (v.x | v.y) b |= 1ULL << (i * 2 + 0);
        if (v.z | v.w) b |= 1ULL << (i * 2 + 1);
      }
    }
    int bh = wi >> 14, q = (wi >> 4) & 1023, kt = wi & 15;
    bits[((size_t)bh * 16 + kt) * 1024 + q] = b;
  } else if (bid < 8192) {
    int i = ((bid - 4096) * 256 + threadIdx.x) * 4;
    float4v v = *(const float4v*)(x + i);
    u16x4 o;
    o[0] = f2bf(v[0]); o[1] = f2bf(v[1]); o[2] = f2bf(v[2]); o[3] = f2bf(v[3]);
    *(u16x4*)(xb + i) = o;
  } else {
    int i = bid - 8192;
    int z = i >> 10, rest = i & 1023;
    const float* W = (z == 0) ? W0 : (z == 1) ? W1 : (z == 2) ? W2 : W3;
    u16* out = Wt + (size_t)z * 1024 * 1024;
    int n0 = (rest & 31) * 32, k0 = (rest >> 5) * 32;
    int tx = threadIdx.x & 31, ty = threadIdx.x >> 5;
#pragma unroll
    for (int j = 0; j < 4; ++j)
      t[ty + 8 * j][tx] = W[(size_t)(k0 + ty + 8 * j) * 1024 + n0 + tx];
    __syncthreads();
#pragma unroll
    for (int j = 0; j < 4; ++j)
      out[(size_t)(n0 + ty + 8 * j) * 1024 + k0 + tx] = f2bf(t[tx][ty + 8 * j]);
  }
}

// ---------- 128xBN bf16 GEMM, A[M][K] x Bt[N][K]^T + bias ----------
template<int BN>
__global__ __launch_bounds__(256)
void gemm_kernel(const u16* __restrict__ A,
                 const u16* __restrict__ Bt0, const u16* __restrict__ Bt1, const u16* __restrict__ Bt2,
                 const float* __restrict__ b0, const float* __restrict__ b1, const float* __restrict__ b2,
                 const float* __restrict__ temp,
                 u16* __restrict__ qb, u16* __restrict__ kb, u16* __restrict__ vT,
                 float* __restrict__ fo, int phase) {
  constexpr int K = 1024;
  constexpr int WN = BN / 2;
  constexpr int NC = WN / 16;
  constexpr int NY = 1024 / BN;
  __shared__ u16 As[128 * 32];
  __shared__ u16 Bs[BN * 32];
  const int tid = threadIdx.x;
  const int lane = tid & 63, w = tid >> 6;
  const int l15 = lane & 15, l4 = lane >> 4;
  const int m0 = blockIdx.x * 128, n0 = (blockIdx.y % NY) * BN;  // y-replicated
  const int z = blockIdx.z;
  const u16* Bt = (z == 0) ? Bt0 : (z == 1) ? Bt1 : Bt2;
  const float* bias = (z == 0) ? b0 : (z == 1) ? b1 : b2;
  const int wr = w >> 1, wc = w & 1;
  const bool ct = (phase == 0) && (z == 2);

  f32x4 acc[4][NC] = {};

  const int c0 = tid, c1 = 256 + tid;
  const u16* ga0 = A + (size_t)(m0 + (c0 >> 2)) * K + (c0 & 3) * 8;
  const u16* ga1 = A + (size_t)(m0 + (c1 >> 2)) * K + (c1 & 3) * 8;
  const u16* gb0 = Bt + (size_t)(n0 + (c0 >> 2)) * K + (c0 & 3) * 8;
  const u16* gb1 = Bt + (size_t)(n0 + (c1 >> 2)) * K + (c1 & 3) * 8;
  u16* la0 = As + c0 * 8;
  u16* la1 = As + c1 * 8;
  u16* lb0 = Bs + c0 * 8;
  u16* lb1 = Bs + c1 * 8;

  for (int kt = 0; kt < K; kt += 32) {
    gload16(ga0 + kt, la0);
    gload16(ga1 + kt, la1);
    gload16(gb0 + kt, lb0);
    if (BN == 128) gload16(gb1 + kt, lb1);
    __syncthreads();
    short8 af[4], bfr[NC];
#pragma unroll
    for (int r = 0; r < 4; ++r)
      af[r] = *(const short8*)(As + (wr * 64 + r * 16 + l15) * 32 + l4 * 8);
#pragma unroll
    for (int c = 0; c < NC; ++c)
      bfr[c] = *(const short8*)(Bs + (wc * WN + c * 16 + l15) * 32 + l4 * 8);
    if (ct) {
#pragma unroll
      for (int r = 0; r < 4; ++r)
#pragma unroll
        for (int c = 0; c < NC; ++c)
          acc[r][c] = __builtin_amdgcn_mfma_f32_16x16x32_bf16(bfr[c], af[r], acc[r][c], 0, 0, 0);
    } else {
#pragma unroll
      for (int r = 0; r < 4; ++r)
#pragma unroll
        for (int c = 0; c < NC; ++c)
          acc[r][c] = __builtin_amdgcn_mfma_f32_16x16x32_bf16(af[r], bfr[c], acc[r][c], 0, 0, 0);
    }
    __syncthreads();
  }

  if (ct) {
    float bvj[NC][4];
#pragma unroll
    for (int c = 0; c < NC; ++c)
#pragma unroll
      for (int j = 0; j < 4; ++j)
        bvj[c][j] = bias[n0 + wc * WN + c * 16 + l4 * 4 + j];
#pragma unroll
    for (int r = 0; r < 4; ++r) {
#pragma unroll
      for (int c = 0; c < NC; ++c) {
#pragma unroll
        for (int j = 0; j < 4; ++j) {
          float val = acc[r][c][j] + bvj[c][j];
          int n = n0 + wc * WN + c * 16 + l4 * 4 + j;
          int mm = m0 + wr * 64 + r * 16 + l15;
          int b = mm >> 10, s = mm & 1023;
          vT[((size_t)b * 1024 + n) * 1024 + s] = f2bf(val);
        }
      }
    }
  } else {
    float bv4[NC], fac4[NC];
#pragma unroll
    for (int c = 0; c < NC; ++c) {
      int col = n0 + wc * WN + c * 16 + l15;
      bv4[c] = bias[col];
      fac4[c] = (phase == 0 && z == 0) ? temp[col >> 6] * 0.18033688011112042f : 1.0f;
    }
#pragma unroll
    for (int r = 0; r < 4; ++r) {
#pragma unroll
      for (int c = 0; c < NC; ++c) {
#pragma unroll
        for (int j = 0; j < 4; ++j) {
          float val = (acc[r][c][j] + bv4[c]) * fac4[c];
          int row = m0 + wr * 64 + r * 16 + l4 * 4 + j;
          int col = n0 + wc * WN + c * 16 + l15;
          if (phase == 0) {
            int b = row >> 10, s = row & 1023, hh = col >> 6, d = col & 63;
            u16* dst = (z == 0) ? qb : kb;
            dst[(((size_t)b * 16 + hh) * 1024 + s) * 64 + d] = f2bf(val);
          } else {
            fo[(size_t)row * 1024 + col] = val;
          }
        }
      }
    }
  }
}

// ---------- per-q-group masked online softmax + P write (scores pre-scaled) ----------
__device__ __forceinline__ void softmax_pwrite(const f32x4* s, u64 wcur,
                                               float& m, float& l, f32x4* oacc,
                                               char* Prow, int swzP, int l4) {
  float xx[4][4];
#pragma unroll
  for (int cb = 0; cb < 4; ++cb) {
    unsigned nib = (unsigned)(wcur >> (cb * 16 + l4 * 4)) & 15u;
#pragma unroll
    for (int j = 0; j < 4; ++j)
      xx[cb][j] = ((nib >> j) & 1) ? s[cb][j] : -1e30f;
  }
  float mt = xx[0][0];
#pragma unroll
  for (int cb = 0; cb < 4; ++cb)
#pragma unroll
    for (int j = 0; j < 4; ++j) mt = fmaxf(mt, xx[cb][j]);
  mt = fmaxf(mt, __shfl_xor(mt, 16));
  mt = fmaxf(mt, __shfl_xor(mt, 32));
  if (!__all(mt <= m + 8.f)) {   // T13 defer-max
    float mnew = fmaxf(m, mt);
    float al = exp2f(m - mnew);
    l *= al;
#pragma unroll
    for (int db = 0; db < 4; ++db) oacc[db] *= al;
    m = mnew;
  }
  float rs = 0.f;
#pragma unroll
  for (int cb = 0; cb < 4; ++cb)
#pragma unroll
    for (int j = 0; j < 4; ++j) {
      xx[cb][j] = exp2f(xx[cb][j] - m);
      rs += xx[cb][j];
    }
  rs += __shfl_xor(rs, 16);
  rs += __shfl_xor(rs, 32);
  l += rs;
#pragma unroll
  for (int cb = 0; cb < 4; ++cb) {
    unsigned w0 = cvtpk(xx[cb][0], xx[cb][1]);
    unsigned w1 = cvtpk(xx[cb][2], xx[cb][3]);
    unsigned o2[2] = {w0, w1};
    *(unsigned long long*)(Prow + ((cb * 32 + l4 * 8) ^ swzP)) = *(unsigned long long*)o2;
  }
}

// ---------- flash attention: KBLK=64 (3 blocks/CU), QBLK=32/wave ----------
__global__ __launch_bounds__(256)
void attn_kernel(const u16* __restrict__ qb, const u16* __restrict__ kb, const u16* __restrict__ vT,
                 const u64* __restrict__ mbits, u16* __restrict__ oh) {
  __shared__ u16 Ks[2][64 * 64];   // 16 KiB
  __shared__ u16 Vs[2][64 * 64];   // 16 KiB
  __shared__ u16 P[4][32 * 64];    // 16 KiB
  const int tid = threadIdx.x, lane = tid & 63, w = tid >> 6;
  const int l15 = lane & 15, l4 = lane >> 4;
  const int id = blockIdx.x;           // 512 blocks: 8 xcd x 8 bh x 8 qx
  const int xcd = id & 7, sl = id >> 3;
  const int bh = xcd * 8 + (sl >> 3), qx = sl & 7;
  const int b = bh >> 4, h = bh & 15;
  const int q0 = qx * 128 + w * 32;
  const u16* qp = qb + ((size_t)bh * 1024 + q0) * 64;
  const u16* kp = kb + (size_t)bh * 1024 * 64;
  const u16* vp = vT + (size_t)bh * 64 * 1024;
  char* Pw = (char*)&P[w][0];
  const int swzP = (l15 & 7) << 4;
  char* ProwA = Pw + l15 * 128;
  char* ProwB = Pw + (16 + l15) * 128;

  const int L0 = tid, L1 = tid + 256;
  const int r0 = L0 >> 3, cc0 = (L0 & 7) ^ (r0 & 7);
  const int r1 = L1 >> 3, cc1 = (L1 & 7) ^ (r1 & 7);
  const int swzK = (l15 & 7) << 3;

  short8 qa0 = *(const short8*)(qp + (size_t)l15 * 64 + l4 * 8);
  short8 qa1 = *(const short8*)(qp + (size_t)l15 * 64 + 32 + l4 * 8);
  short8 qb0 = *(const short8*)(qp + (size_t)(16 + l15) * 64 + l4 * 8);
  short8 qb1 = *(const short8*)(qp + (size_t)(16 + l15) * 64 + 32 + l4 * 8);

  float ma = -1e30f, la = 0.f, mbv = -1e30f, lb = 0.f;
  f32x4 oa[4] = {}, ob[4] = {};

  const u64* mba = mbits + (size_t)bh * 16 * 1024 + q0 + l15;
  u64 wa = mba[0], wb = mba[16];

  gload16(kp + (size_t)r0 * 64 + cc0 * 8, &Ks[0][L0 * 8]);
  gload16(kp + (size_t)r1 * 64 + cc1 * 8, &Ks[0][L1 * 8]);
  gload16(vp + (size_t)r0 * 1024 + cc0 * 8, &Vs[0][L0 * 8]);
  gload16(vp + (size_t)r1 * 1024 + cc1 * 8, &Vs[0][L1 * 8]);

  for (int t = 0; t < 16; ++t) {
    const int buf = t & 1;
    __syncthreads();

    if (t < 15) {
      const int k1 = (t + 1) * 64;
      gload16(kp + (size_t)(k1 + r0) * 64 + cc0 * 8, &Ks[buf ^ 1][L0 * 8]);
      gload16(kp + (size_t)(k1 + r1) * 64 + cc1 * 8, &Ks[buf ^ 1][L1 * 8]);
      gload16(vp + (size_t)r0 * 1024 + k1 + cc0 * 8, &Vs[buf ^ 1][L0 * 8]);
      gload16(vp + (size_t)r1 * 1024 + k1 + cc1 * 8, &Vs[buf ^ 1][L1 * 8]);
    }
    u64 wan = 0, wbn = 0;
    if (t < 15) { wan = mba[(t + 1) * 1024]; wbn = mba[(t + 1) * 1024 + 16]; }

    f32x4 sa[4] = {}, sb[4] = {};
    __builtin_amdgcn_s_setprio(1);
#pragma unroll
    for (int cb = 0; cb < 4; ++cb) {
      const u16* kr = &Ks[buf][(cb * 16 + l15) * 64];
      short8 kf0 = *(const short8*)(kr + ((l4 * 8) ^ swzK));
      short8 kf1 = *(const short8*)(kr + ((32 + l4 * 8) ^ swzK));
      sa[cb] = __builtin_amdgcn_mfma_f32_16x16x32_bf16(kf0, qa0, sa[cb], 0, 0, 0);
      sa[cb] = __builtin_amdgcn_mfma_f32_16x16x32_bf16(kf1, qa1, sa[cb], 0, 0, 0);
      sb[cb] = __builtin_amdgcn_mfma_f32_16x16x32_bf16(kf0, qb0, sb[cb], 0, 0, 0);
      sb[cb] = __builtin_amdgcn_mfma_f32_16x16x32_bf16(kf1, qb1, sb[cb], 0, 0, 0);
    }
    __builtin_amdgcn_s_setprio(0);

    softmax_pwrite(sa, wa, ma, la, oa, ProwA, swzP, l4);
    softmax_pwrite(sb, wb, mbv, lb, ob, ProwB, swzP, l4);

    __builtin_amdgcn_s_setprio(1);
#pragma unroll
    for (int ks = 0; ks < 2; ++ks) {
      short8 pa = *(const short8*)(ProwA + ((ks * 64 + l4 * 16) ^ swzP));
      short8 pbf = *(const short8*)(ProwB + ((ks * 64 + l4 * 16) ^ swzP));
#pragma unroll
      for (int db = 0; db < 4; ++db) {
        short8 vf = *(const short8*)(&Vs[buf][(db * 16 + l15) * 64 + ((ks * 32 + l4 * 8) ^ swzK)]);
        oa[db] = __builtin_amdgcn_mfma_f32_16x16x32_bf16(vf, pa, oa[db], 0, 0, 0);
        ob[db] = __builtin_amdgcn_mfma_f32_16x16x32_bf16(vf, pbf, ob[db], 0, 0, 0);
      }
    }
    __builtin_amdgcn_s_setprio(0);
    wa = wan; wb = wbn;
  }

  float rla = 1.f / la, rlb = 1.f / lb;
  u16* orowA = oh + ((size_t)b * 1024 + q0 + l15) * 1024 + h * 64;
  u16* orowB = oh + ((size_t)b * 1024 + q0 + 16 + l15) * 1024 + h * 64;
#pragma unroll
  for (int db = 0; db < 4; ++db) {
    unsigned a0 = cvtpk(oa[db][0] * rla, oa[db][1] * rla);
    unsigned a1 = cvtpk(oa[db][2] * rla, oa[db][3] * rla);
    unsigned b0 = cvtpk(ob[db][0] * rlb, ob[db][1] * rlb);
    unsigned b1 = cvtpk(ob[db][2] * rlb, ob[db][3] * rlb);
    unsigned oA[2] = {a0, a1}, oB[2] = {b0, b1};
    *(unsigned long long*)(orowA + db * 16 + l4 * 4) = *(unsigned long long*)oA;
    *(unsigned long long*)(orowB + db * 16 + l4 * 4) = *(unsigned long long*)oB;
  }
}

// ---------- launch ----------
extern "C" void kernel_launch(void* const* d_in, const int* in_sizes, int n_in,
                              void* d_out, int out_size, void* d_ws, size_t ws_size,
                              hipStream_t stream) {
  const float* x = (const float*)d_in[0];
  const float* Wq = (const float*)d_in[1];
  const float* bq = (const float*)d_in[2];
  const float* Wk = (const float*)d_in[3];
  const float* bk = (const float*)d_in[4];
  const float* Wv = (const float*)d_in[5];
  const float* bv = (const float*)d_in[6];
  const float* Wo = (const float*)d_in[7];
  const float* bo = (const float*)d_in[8];
  const float* temp = (const float*)d_in[9];
  const void* mask = (const void*)d_in[10];

  char* ws = (char*)d_ws;
  u16* xb = (u16*)(ws + 256);
  u16* Wt = xb + (size_t)4 * 1024 * 1024;
  u16* qbuf = Wt + (size_t)4 * 1024 * 1024;
  u16* kbuf = qbuf + (size_t)4 * 1024 * 1024;
  u16* vTb = kbuf + (size_t)4 * 1024 * 1024;
  u64* mbits = (u64*)(vTb + (size_t)4 * 1024 * 1024);
  u16* oh = xb;

  prep_kernel<<<dim3(12288, REP_PREP), 256, 0, stream>>>(
      mask, mbits, x, xb, Wq, Wk, Wv, Wo, Wt);
  gemm_kernel<128><<<dim3(32, 8 * REP_QKV, 3), 256, 0, stream>>>(
      xb, Wt, Wt + 1024 * 1024, Wt + 2 * 1024 * 1024,
      bq, bk, bv, temp, qbuf, kbuf, vTb, nullptr, 0);
  attn_kernel<<<dim3(512, REP_ATTN), 256, 0, stream>>>(qbuf, kbuf, vTb, mbits, oh);
  gemm_kernel<64><<<dim3(32, 16 * REP_OPRJ, 1), 256, 0, stream>>>(
      oh, Wt + 3 * 1024 * 1024, nullptr, nullptr,
      bo, nullptr, nullptr, temp, nullptr, nullptr, nullptr, (float*)d_out, 1);
}

// Round 7
// 1362.421 us; speedup vs baseline: 1.5041x; 1.5041x over previous
//
#include <hip/hip_runtime.h>

typedef unsigned short u16;
typedef short short8 __attribute__((ext_vector_type(8)));
typedef float f32x4 __attribute__((ext_vector_type(4)));
typedef float float4v __attribute__((ext_vector_type(4)));
typedef u16 u16x4 __attribute__((ext_vector_type(4)));
typedef unsigned long long u64;

// ======== DIAGNOSTIC: attn x24 / prep x4, replicas write DISJOINT scratch ====
#define REP_PREP 4
#define REP_ATTN 24

// ---------- helpers ----------
__device__ __forceinline__ u16 f2bf(float f) {
  union { float f; unsigned u; } v; v.f = f;
  unsigned r = v.u + 0x7FFFu + ((v.u >> 16) & 1u);   // round-to-nearest-even
  return (u16)(r >> 16);
}

__device__ __forceinline__ unsigned cvtpk(float lo, float hi) {
  unsigned r;
  asm("v_cvt_pk_bf16_f32 %0, %1, %2" : "=v"(r) : "v"(lo), "v"(hi));
  return r;
}

__device__ __forceinline__ void gload16(const u16* g, u16* l) {
  __builtin_amdgcn_global_load_lds(
      (const __attribute__((address_space(1))) void*)g,
      (__attribute__((address_space(3))) void*)l, 16, 0, 0);
}

// ---------- merged prep: maskbits (0..4095), xcvt (4096..8191), wcvt (8192..12287) ----------
__global__ __launch_bounds__(256)
void prep_kernel(const void* __restrict__ mask, u64* __restrict__ bits,
                 const float* __restrict__ x, u16* __restrict__ xb,
                 const float* __restrict__ W0, const float* __restrict__ W1,
                 const float* __restrict__ W2, const float* __restrict__ W3,
                 u16* __restrict__ Wt, char* __restrict__ diag) {
  __shared__ float t[32][33];
  __shared__ int sf;
  const int rep = blockIdx.y;
  if (rep) {  // diagnostic replicas write to private scratch (no contention)
    size_t off = (size_t)(rep - 1) * (32u << 20);
    bits = (u64*)(diag + off);
    xb = (u16*)(diag + off + (8u << 20));
    Wt = (u16*)(diag + off + (16u << 20));
  }
  const int bid = blockIdx.x;
  if (bid < 4096) {
    if (threadIdx.x == 0) sf = 0;
    __syncthreads();
    {
      uint4 v = ((const uint4*)mask)[threadIdx.x];
      unsigned xs[4] = {v.x, v.y, v.z, v.w};
      int f = 0;
#pragma unroll
      for (int d = 0; d < 4; ++d) {
        unsigned u = xs[d];
        if (u == 0x3F800000u) f |= 1;
        if (u & 0xFFFFFF00u) f |= 2;
        if ((d & 1) && u) f |= 4;
      }
      if (f) atomicOr(&sf, f);
    }
    __syncthreads();
    const int fl = sf;
    const int fmt = (fl & 1) ? 2 : ((fl & 2) ? 0 : ((fl & 4) ? 1 : 3));

    const int wi = bid * 256 + threadIdx.x;  // 1M words
    u64 b = 0;
    if (fmt == 0) {
      const uint4* mp = (const uint4*)mask + (size_t)wi * 4;
#pragma unroll
      for (int i = 0; i < 4; ++i) {
        uint4 v = mp[i];
        unsigned xw[4] = {v.x, v.y, v.z, v.w};
#pragma unroll
        for (int d = 0; d < 4; ++d)
#pragma unroll
          for (int by = 0; by < 4; ++by)
            if (xw[d] & (0xFFu << (by * 8))) b |= 1ULL << (i * 16 + d * 4 + by);
      }
    } else if (fmt != 3) {
      const uint4* mp = (const uint4*)mask + (size_t)wi * 16;
#pragma unroll
      for (int i = 0; i < 16; ++i) {
        uint4 v = mp[i];
        if (v.x) b |= 1ULL << (i * 4 + 0);
        if (v.y) b |= 1ULL << (i * 4 + 1);
        if (v.z) b |= 1ULL << (i * 4 + 2);
        if (v.w) b |= 1ULL << (i * 4 + 3);
      }
    } else {
      const uint4* mp = (const uint4*)mask + (size_t)wi * 32;
#pragma unroll
      for (int i = 0; i < 32; ++i) {
        uint4 v = mp[i];
        if (v.x | v.y) b |= 1ULL << (i * 2 + 0);
        if (v.z | v.w) b |= 1ULL << (i * 2 + 1);
      }
    }
    int bh = wi >> 14, q = (wi >> 4) & 1023, kt = wi & 15;
    bits[((size_t)bh * 16 + kt) * 1024 + q] = b;
  } else if (bid < 8192) {
    int i = ((bid - 4096) * 256 + threadIdx.x) * 4;
    float4v v = *(const float4v*)(x + i);
    u16x4 o;
    o[0] = f2bf(v[0]); o[1] = f2bf(v[1]); o[2] = f2bf(v[2]); o[3] = f2bf(v[3]);
    *(u16x4*)(xb + i) = o;
  } else {
    int i = bid - 8192;
    int z = i >> 10, rest = i & 1023;
    const float* W = (z == 0) ? W0 : (z == 1) ? W1 : (z == 2) ? W2 : W3;
    u16* out = Wt + (size_t)z * 1024 * 1024;
    int n0 = (rest & 31) * 32, k0 = (rest >> 5) * 32;
    int tx = threadIdx.x & 31, ty = threadIdx.x >> 5;
#pragma unroll
    for (int j = 0; j < 4; ++j)
      t[ty + 8 * j][tx] = W[(size_t)(k0 + ty + 8 * j) * 1024 + n0 + tx];
    __syncthreads();
#pragma unroll
    for (int j = 0; j < 4; ++j)
      out[(size_t)(n0 + ty + 8 * j) * 1024 + k0 + tx] = f2bf(t[tx][ty + 8 * j]);
  }
}

// ---------- 128xBN bf16 GEMM, all-swapped MFMA: acc holds C^T ----------
// acc[r][c]: local row = n-part (c*16 + l4*4 + j), local col = m-part (r*16 + l15)
// phase 0: z=0 -> q (pre-scaled, u64 stores), z=1 -> k (u64), z=2 -> vT (lane-coalesced)
// phase 1: f32 out, float4 stores
template<int BN>
__global__ __launch_bounds__(256)
void gemm_kernel(const u16* __restrict__ A,
                 const u16* __restrict__ Bt0, const u16* __restrict__ Bt1, const u16* __restrict__ Bt2,
                 const float* __restrict__ b0, const float* __restrict__ b1, const float* __restrict__ b2,
                 const float* __restrict__ temp,
                 u16* __restrict__ qb, u16* __restrict__ kb, u16* __restrict__ vT,
                 float* __restrict__ fo, int phase) {
  constexpr int K = 1024;
  constexpr int WN = BN / 2;
  constexpr int NC = WN / 16;
  __shared__ u16 As[128 * 32];
  __shared__ u16 Bs[BN * 32];
  const int tid = threadIdx.x;
  const int lane = tid & 63, w = tid >> 6;
  const int l15 = lane & 15, l4 = lane >> 4;
  const int m0 = blockIdx.x * 128, n0 = blockIdx.y * BN;
  const int z = blockIdx.z;
  const u16* Bt = (z == 0) ? Bt0 : (z == 1) ? Bt1 : Bt2;
  const float* bias = (z == 0) ? b0 : (z == 1) ? b1 : b2;
  const int wr = w >> 1, wc = w & 1;

  f32x4 acc[4][NC] = {};

  const int c0 = tid, c1 = 256 + tid;
  const u16* ga0 = A + (size_t)(m0 + (c0 >> 2)) * K + (c0 & 3) * 8;
  const u16* ga1 = A + (size_t)(m0 + (c1 >> 2)) * K + (c1 & 3) * 8;
  const u16* gb0 = Bt + (size_t)(n0 + (c0 >> 2)) * K + (c0 & 3) * 8;
  const u16* gb1 = Bt + (size_t)(n0 + (c1 >> 2)) * K + (c1 & 3) * 8;
  u16* la0 = As + c0 * 8;
  u16* la1 = As + c1 * 8;
  u16* lb0 = Bs + c0 * 8;
  u16* lb1 = Bs + c1 * 8;

  for (int kt = 0; kt < K; kt += 32) {
    gload16(ga0 + kt, la0);
    gload16(ga1 + kt, la1);
    gload16(gb0 + kt, lb0);
    if (BN == 128) gload16(gb1 + kt, lb1);
    __syncthreads();
    short8 af[4], bfr[NC];
#pragma unroll
    for (int r = 0; r < 4; ++r)
      af[r] = *(const short8*)(As + (wr * 64 + r * 16 + l15) * 32 + l4 * 8);
#pragma unroll
    for (int c = 0; c < NC; ++c)
      bfr[c] = *(const short8*)(Bs + (wc * WN + c * 16 + l15) * 32 + l4 * 8);
#pragma unroll
    for (int r = 0; r < 4; ++r)
#pragma unroll
      for (int c = 0; c < NC; ++c)
        acc[r][c] = __builtin_amdgcn_mfma_f32_16x16x32_bf16(bfr[c], af[r], acc[r][c], 0, 0, 0);
    __syncthreads();
  }

  float bvj[NC][4];
#pragma unroll
  for (int c = 0; c < NC; ++c)
#pragma unroll
    for (int j = 0; j < 4; ++j)
      bvj[c][j] = bias[n0 + wc * WN + c * 16 + l4 * 4 + j];
  const float fac = (phase == 0 && z == 0)
      ? temp[(n0 + wc * WN) >> 6] * 0.18033688011112042f : 1.0f;

#pragma unroll
  for (int r = 0; r < 4; ++r) {
    const int mm = m0 + wr * 64 + r * 16 + l15;   // b*1024+s, lane-contiguous
    const int b = mm >> 10, s = mm & 1023;
#pragma unroll
    for (int c = 0; c < NC; ++c) {
      const int n = n0 + wc * WN + c * 16 + l4 * 4;  // 4 consecutive n per thread
      if (phase == 1) {
        float4v o;
#pragma unroll
        for (int j = 0; j < 4; ++j) o[j] = acc[r][c][j] + bvj[c][j];
        *(float4v*)(fo + (size_t)mm * 1024 + n) = o;
      } else if (z == 2) {
#pragma unroll
        for (int j = 0; j < 4; ++j)
          vT[((size_t)b * 1024 + n + j) * 1024 + s] = f2bf(acc[r][c][j] + bvj[c][j]);
      } else {
        unsigned lo = cvtpk((acc[r][c][0] + bvj[c][0]) * fac, (acc[r][c][1] + bvj[c][1]) * fac);
        unsigned hi = cvtpk((acc[r][c][2] + bvj[c][2]) * fac, (acc[r][c][3] + bvj[c][3]) * fac);
        unsigned o2[2] = {lo, hi};
        int hh = n >> 6, d = n & 63;
        u16* dst = (z == 0) ? qb : kb;
        *(unsigned long long*)(dst + ((((size_t)b * 16 + hh) * 1024 + s) * 64 + d)) =
            *(unsigned long long*)o2;
      }
    }
  }
}

// ---------- per-q-group masked online softmax + P write ----------
__device__ __forceinline__ void softmax_pwrite(const f32x4* s, u64 wcur,
                                               float& m, float& l, f32x4* oacc,
                                               char* Prow, int swzP, int l4) {
  float xx[4][4];
#pragma unroll
  for (int cb = 0; cb < 4; ++cb) {
    unsigned nib = (unsigned)(wcur >> (cb * 16 + l4 * 4)) & 15u;
#pragma unroll
    for (int j = 0; j < 4; ++j)
      xx[cb][j] = ((nib >> j) & 1) ? s[cb][j] : -1e30f;
  }
  float mt = xx[0][0];
#pragma unroll
  for (int cb = 0; cb < 4; ++cb)
#pragma unroll
    for (int j = 0; j < 4; ++j) mt = fmaxf(mt, xx[cb][j]);
  mt = fmaxf(mt, __shfl_xor(mt, 16));
  mt = fmaxf(mt, __shfl_xor(mt, 32));
  if (!__all(mt <= m + 8.f)) {   // T13 defer-max
    float mnew = fmaxf(m, mt);
    float al = exp2f(m - mnew);
    l *= al;
#pragma unroll
    for (int db = 0; db < 4; ++db) oacc[db] *= al;
    m = mnew;
  }
  float rs = 0.f;
#pragma unroll
  for (int cb = 0; cb < 4; ++cb)
#pragma unroll
    for (int j = 0; j < 4; ++j) {
      xx[cb][j] = exp2f(xx[cb][j] - m);
      rs += xx[cb][j];
    }
  rs += __shfl_xor(rs, 16);
  rs += __shfl_xor(rs, 32);
  l += rs;
#pragma unroll
  for (int cb = 0; cb < 4; ++cb) {
    unsigned w0 = cvtpk(xx[cb][0], xx[cb][1]);
    unsigned w1 = cvtpk(xx[cb][2], xx[cb][3]);
    unsigned o2[2] = {w0, w1};
    *(unsigned long long*)(Prow + ((cb * 32 + l4 * 8) ^ swzP)) = *(unsigned long long*)o2;
  }
}

// ---------- flash attention: KBLK=64, QBLK=32/wave (x24 diagnostic replication) ----------
__global__ __launch_bounds__(256)
void attn_kernel(const u16* __restrict__ qb, const u16* __restrict__ kb, const u16* __restrict__ vT,
                 const u64* __restrict__ mbits, u16* __restrict__ oh,
                 u16* __restrict__ oh_diag) {
  __shared__ u16 Ks[2][64 * 64];
  __shared__ u16 Vs[2][64 * 64];
  __shared__ u16 P[4][32 * 64];
  const int tid = threadIdx.x, lane = tid & 63, w = tid >> 6;
  const int l15 = lane & 15, l4 = lane >> 4;
  const int rep = blockIdx.y;
  if (rep) oh = oh_diag + (size_t)(rep - 1) * (4u << 20);  // disjoint 8MB per replica
  const int id = blockIdx.x;           // 512: 8 xcd x 8 bh x 8 qx
  const int xcd = id & 7, sl = id >> 3;
  const int bh = xcd * 8 + (sl >> 3), qx = sl & 7;
  const int b = bh >> 4, h = bh & 15;
  const int q0 = qx * 128 + w * 32;
  const u16* qp = qb + ((size_t)bh * 1024 + q0) * 64;
  const u16* kp = kb + (size_t)bh * 1024 * 64;
  const u16* vp = vT + (size_t)bh * 64 * 1024;
  char* Pw = (char*)&P[w][0];
  const int swzP = (l15 & 7) << 4;
  char* ProwA = Pw + l15 * 128;
  char* ProwB = Pw + (16 + l15) * 128;

  const int L0 = tid, L1 = tid + 256;
  const int r0 = L0 >> 3, cc0 = (L0 & 7) ^ (r0 & 7);
  const int r1 = L1 >> 3, cc1 = (L1 & 7) ^ (r1 & 7);
  const int swzK = (l15 & 7) << 3;

  short8 qa0 = *(const short8*)(qp + (size_t)l15 * 64 + l4 * 8);
  short8 qa1 = *(const short8*)(qp + (size_t)l15 * 64 + 32 + l4 * 8);
  short8 qb0 = *(const short8*)(qp + (size_t)(16 + l15) * 64 + l4 * 8);
  short8 qb1 = *(const short8*)(qp + (size_t)(16 + l15) * 64 + 32 + l4 * 8);

  float ma = -1e30f, la = 0.f, mbv = -1e30f, lb = 0.f;
  f32x4 oa[4] = {}, ob[4] = {};

  const u64* mba = mbits + (size_t)bh * 16 * 1024 + q0 + l15;
  u64 wa = mba[0], wb = mba[16];

  gload16(kp + (size_t)r0 * 64 + cc0 * 8, &Ks[0][L0 * 8]);
  gload16(kp + (size_t)r1 * 64 + cc1 * 8, &Ks[0][L1 * 8]);
  gload16(vp + (size_t)r0 * 1024 + cc0 * 8, &Vs[0][L0 * 8]);
  gload16(vp + (size_t)r1 * 1024 + cc1 * 8, &Vs[0][L1 * 8]);

  for (int t = 0; t < 16; ++t) {
    const int buf = t & 1;
    __syncthreads();

    if (t < 15) {
      const int k1 = (t + 1) * 64;
      gload16(kp + (size_t)(k1 + r0) * 64 + cc0 * 8, &Ks[buf ^ 1][L0 * 8]);
      gload16(kp + (size_t)(k1 + r1) * 64 + cc1 * 8, &Ks[buf ^ 1][L1 * 8]);
      gload16(vp + (size_t)r0 * 1024 + k1 + cc0 * 8, &Vs[buf ^ 1][L0 * 8]);
      gload16(vp + (size_t)r1 * 1024 + k1 + cc1 * 8, &Vs[buf ^ 1][L1 * 8]);
    }
    u64 wan = 0, wbn = 0;
    if (t < 15) { wan = mba[(t + 1) * 1024]; wbn = mba[(t + 1) * 1024 + 16]; }

    f32x4 sa[4] = {}, sb[4] = {};
    __builtin_amdgcn_s_setprio(1);
#pragma unroll
    for (int cb = 0; cb < 4; ++cb) {
      const u16* kr = &Ks[buf][(cb * 16 + l15) * 64];
      short8 kf0 = *(const short8*)(kr + ((l4 * 8) ^ swzK));
      short8 kf1 = *(const short8*)(kr + ((32 + l4 * 8) ^ swzK));
      sa[cb] = __builtin_amdgcn_mfma_f32_16x16x32_bf16(kf0, qa0, sa[cb], 0, 0, 0);
      sa[cb] = __builtin_amdgcn_mfma_f32_16x16x32_bf16(kf1, qa1, sa[cb], 0, 0, 0);
      sb[cb] = __builtin_amdgcn_mfma_f32_16x16x32_bf16(kf0, qb0, sb[cb], 0, 0, 0);
      sb[cb] = __builtin_amdgcn_mfma_f32_16x16x32_bf16(kf1, qb1, sb[cb], 0, 0, 0);
    }
    __builtin_amdgcn_s_setprio(0);

    softmax_pwrite(sa, wa, ma, la, oa, ProwA, swzP, l4);
    softmax_pwrite(sb, wb, mbv, lb, ob, ProwB, swzP, l4);

    __builtin_amdgcn_s_setprio(1);
#pragma unroll
    for (int ks = 0; ks < 2; ++ks) {
      short8 pa = *(const short8*)(ProwA + ((ks * 64 + l4 * 16) ^ swzP));
      short8 pbf = *(const short8*)(ProwB + ((ks * 64 + l4 * 16) ^ swzP));
#pragma unroll
      for (int db = 0; db < 4; ++db) {
        short8 vf = *(const short8*)(&Vs[buf][(db * 16 + l15) * 64 + ((ks * 32 + l4 * 8) ^ swzK)]);
        oa[db] = __builtin_amdgcn_mfma_f32_16x16x32_bf16(vf, pa, oa[db], 0, 0, 0);
        ob[db] = __builtin_amdgcn_mfma_f32_16x16x32_bf16(vf, pbf, ob[db], 0, 0, 0);
      }
    }
    __builtin_amdgcn_s_setprio(0);
    wa = wan; wb = wbn;
  }

  float rla = 1.f / la, rlb = 1.f / lb;
  u16* orowA = oh + ((size_t)b * 1024 + q0 + l15) * 1024 + h * 64;
  u16* orowB = oh + ((size_t)b * 1024 + q0 + 16 + l15) * 1024 + h * 64;
#pragma unroll
  for (int db = 0; db < 4; ++db) {
    unsigned a0 = cvtpk(oa[db][0] * rla, oa[db][1] * rla);
    unsigned a1 = cvtpk(oa[db][2] * rla, oa[db][3] * rla);
    unsigned b0 = cvtpk(ob[db][0] * rlb, ob[db][1] * rlb);
    unsigned b1 = cvtpk(ob[db][2] * rlb, ob[db][3] * rlb);
    unsigned oA[2] = {a0, a1}, oB[2] = {b0, b1};
    *(unsigned long long*)(orowA + db * 16 + l4 * 4) = *(unsigned long long*)oA;
    *(unsigned long long*)(orowB + db * 16 + l4 * 4) = *(unsigned long long*)oB;
  }
}

// ---------- launch ----------
extern "C" void kernel_launch(void* const* d_in, const int* in_sizes, int n_in,
                              void* d_out, int out_size, void* d_ws, size_t ws_size,
                              hipStream_t stream) {
  const float* x = (const float*)d_in[0];
  const float* Wq = (const float*)d_in[1];
  const float* bq = (const float*)d_in[2];
  const float* Wk = (const float*)d_in[3];
  const float* bk = (const float*)d_in[4];
  const float* Wv = (const float*)d_in[5];
  const float* bv = (const float*)d_in[6];
  const float* Wo = (const float*)d_in[7];
  const float* bo = (const float*)d_in[8];
  const float* temp = (const float*)d_in[9];
  const void* mask = (const void*)d_in[10];

  char* ws = (char*)d_ws;
  u16* xb = (u16*)(ws + 256);
  u16* Wt = xb + (size_t)4 * 1024 * 1024;
  u16* qbuf = Wt + (size_t)4 * 1024 * 1024;
  u16* kbuf = qbuf + (size_t)4 * 1024 * 1024;
  u16* vTb = kbuf + (size_t)4 * 1024 * 1024;
  u64* mbits = (u64*)(vTb + (size_t)4 * 1024 * 1024);
  u16* oh = xb;
  char* diagP = ws + ((size_t)64 << 20);            // 3 x 32MB prep replicas
  u16* diagA = (u16*)(ws + ((size_t)192 << 20));    // 23 x 8MB attn replicas

  prep_kernel<<<dim3(12288, REP_PREP), 256, 0, stream>>>(
      mask, mbits, x, xb, Wq, Wk, Wv, Wo, Wt, diagP);
  gemm_kernel<128><<<dim3(32, 8, 3), 256, 0, stream>>>(
      xb, Wt, Wt + 1024 * 1024, Wt + 2 * 1024 * 1024,
      bq, bk, bv, temp, qbuf, kbuf, vTb, nullptr, 0);
  attn_kernel<<<dim3(512, REP_ATTN), 256, 0, stream>>>(qbuf, kbuf, vTb, mbits, oh, diagA);
  gemm_kernel<64><<<dim3(32, 16, 1), 256, 0, stream>>>(
      oh, Wt + 3 * 1024 * 1024, nullptr, nullptr,
      bo, nullptr, nullptr, temp, nullptr, nullptr, nullptr, (float*)d_out, 1);
}

// Round 8
// 188.434 us; speedup vs baseline: 10.8751x; 7.2302x over previous
//
#include <hip/hip_runtime.h>

typedef unsigned short u16;
typedef short short8 __attribute__((ext_vector_type(8)));
typedef float f32x4 __attribute__((ext_vector_type(4)));
typedef float float4v __attribute__((ext_vector_type(4)));
typedef u16 u16x4 __attribute__((ext_vector_type(4)));
typedef unsigned uint2v __attribute__((ext_vector_type(2)));
typedef unsigned long long u64;

// ---------- helpers ----------
__device__ __forceinline__ u16 f2bf(float f) {
  union { float f; unsigned u; } v; v.f = f;
  unsigned r = v.u + 0x7FFFu + ((v.u >> 16) & 1u);   // round-to-nearest-even
  return (u16)(r >> 16);
}

__device__ __forceinline__ unsigned cvtpk(float lo, float hi) {
  unsigned r;
  asm("v_cvt_pk_bf16_f32 %0, %1, %2" : "=v"(r) : "v"(lo), "v"(hi));
  return r;
}

__device__ __forceinline__ void gload16(const u16* g, u16* l) {
  __builtin_amdgcn_global_load_lds(
      (const __attribute__((address_space(1))) void*)g,
      (__attribute__((address_space(3))) void*)l, 16, 0, 0);
}

union PackSS { unsigned u[4]; short8 s; };

// ---------- merged prep: maskbits (0..4095), xcvt (4096..8191), wcvt (8192..12287) ----------
__global__ __launch_bounds__(256)
void prep_kernel(const void* __restrict__ mask, u64* __restrict__ bits,
                 const float* __restrict__ x, u16* __restrict__ xb,
                 const float* __restrict__ W0, const float* __restrict__ W1,
                 const float* __restrict__ W2, const float* __restrict__ W3,
                 u16* __restrict__ Wt) {
  __shared__ float t[32][33];
  __shared__ int sf;
  const int bid = blockIdx.x;
  if (bid < 4096) {
    // ---- maskbits with self-detected dtype (fmt: 0=u8, 1=i32, 2=f32, 3=i64) ----
    if (threadIdx.x == 0) sf = 0;
    __syncthreads();
    {
      uint4 v = ((const uint4*)mask)[threadIdx.x];
      unsigned xs[4] = {v.x, v.y, v.z, v.w};
      int f = 0;
#pragma unroll
      for (int d = 0; d < 4; ++d) {
        unsigned u = xs[d];
        if (u == 0x3F800000u) f |= 1;
        if (u & 0xFFFFFF00u) f |= 2;
        if ((d & 1) && u) f |= 4;
      }
      if (f) atomicOr(&sf, f);
    }
    __syncthreads();
    const int fl = sf;
    const int fmt = (fl & 1) ? 2 : ((fl & 2) ? 0 : ((fl & 4) ? 1 : 3));

    const int wi = bid * 256 + threadIdx.x;  // 1M words
    u64 b = 0;
    if (fmt == 0) {
      const uint4* mp = (const uint4*)mask + (size_t)wi * 4;
#pragma unroll
      for (int i = 0; i < 4; ++i) {
        uint4 v = mp[i];
        unsigned xw[4] = {v.x, v.y, v.z, v.w};
#pragma unroll
        for (int d = 0; d < 4; ++d)
#pragma unroll
          for (int by = 0; by < 4; ++by)
            if (xw[d] & (0xFFu << (by * 8))) b |= 1ULL << (i * 16 + d * 4 + by);
      }
    } else if (fmt != 3) {
      const uint4* mp = (const uint4*)mask + (size_t)wi * 16;
#pragma unroll
      for (int i = 0; i < 16; ++i) {
        uint4 v = mp[i];
        if (v.x) b |= 1ULL << (i * 4 + 0);
        if (v.y) b |= 1ULL << (i * 4 + 1);
        if (v.z) b |= 1ULL << (i * 4 + 2);
        if (v.w) b |= 1ULL << (i * 4 + 3);
      }
    } else {
      const uint4* mp = (const uint4*)mask + (size_t)wi * 32;
#pragma unroll
      for (int i = 0; i < 32; ++i) {
        uint4 v = mp[i];
        if (v.x | v.y) b |= 1ULL << (i * 2 + 0);
        if (v.z | v.w) b |= 1ULL << (i * 2 + 1);
      }
    }
    int bh = wi >> 14, q = (wi >> 4) & 1023, kt = wi & 15;
    bits[((size_t)bh * 16 + kt) * 1024 + q] = b;
  } else if (bid < 8192) {
    int i = ((bid - 4096) * 256 + threadIdx.x) * 4;
    float4v v = *(const float4v*)(x + i);
    u16x4 o;
    o[0] = f2bf(v[0]); o[1] = f2bf(v[1]); o[2] = f2bf(v[2]); o[3] = f2bf(v[3]);
    *(u16x4*)(xb + i) = o;
  } else {
    int i = bid - 8192;
    int z = i >> 10, rest = i & 1023;
    const float* W = (z == 0) ? W0 : (z == 1) ? W1 : (z == 2) ? W2 : W3;
    u16* out = Wt + (size_t)z * 1024 * 1024;
    int n0 = (rest & 31) * 32, k0 = (rest >> 5) * 32;
    int tx = threadIdx.x & 31, ty = threadIdx.x >> 5;
#pragma unroll
    for (int j = 0; j < 4; ++j)
      t[ty + 8 * j][tx] = W[(size_t)(k0 + ty + 8 * j) * 1024 + n0 + tx];
    __syncthreads();
#pragma unroll
    for (int j = 0; j < 4; ++j)
      out[(size_t)(n0 + ty + 8 * j) * 1024 + k0 + tx] = f2bf(t[tx][ty + 8 * j]);
  }
}

// ---------- 128xBN bf16 GEMM, all-swapped MFMA: acc holds C^T ----------
template<int BN>
__global__ __launch_bounds__(256)
void gemm_kernel(const u16* __restrict__ A,
                 const u16* __restrict__ Bt0, const u16* __restrict__ Bt1, const u16* __restrict__ Bt2,
                 const float* __restrict__ b0, const float* __restrict__ b1, const float* __restrict__ b2,
                 const float* __restrict__ temp,
                 u16* __restrict__ qb, u16* __restrict__ kb, u16* __restrict__ vT,
                 float* __restrict__ fo, int phase) {
  constexpr int K = 1024;
  constexpr int WN = BN / 2;
  constexpr int NC = WN / 16;
  __shared__ u16 As[128 * 32];
  __shared__ u16 Bs[BN * 32];
  const int tid = threadIdx.x;
  const int lane = tid & 63, w = tid >> 6;
  const int l15 = lane & 15, l4 = lane >> 4;
  const int m0 = blockIdx.x * 128, n0 = blockIdx.y * BN;
  const int z = blockIdx.z;
  const u16* Bt = (z == 0) ? Bt0 : (z == 1) ? Bt1 : Bt2;
  const float* bias = (z == 0) ? b0 : (z == 1) ? b1 : b2;
  const int wr = w >> 1, wc = w & 1;

  f32x4 acc[4][NC] = {};

  const int c0 = tid, c1 = 256 + tid;
  const u16* ga0 = A + (size_t)(m0 + (c0 >> 2)) * K + (c0 & 3) * 8;
  const u16* ga1 = A + (size_t)(m0 + (c1 >> 2)) * K + (c1 & 3) * 8;
  const u16* gb0 = Bt + (size_t)(n0 + (c0 >> 2)) * K + (c0 & 3) * 8;
  const u16* gb1 = Bt + (size_t)(n0 + (c1 >> 2)) * K + (c1 & 3) * 8;
  u16* la0 = As + c0 * 8;
  u16* la1 = As + c1 * 8;
  u16* lb0 = Bs + c0 * 8;
  u16* lb1 = Bs + c1 * 8;

  for (int kt = 0; kt < K; kt += 32) {
    gload16(ga0 + kt, la0);
    gload16(ga1 + kt, la1);
    gload16(gb0 + kt, lb0);
    if (BN == 128) gload16(gb1 + kt, lb1);
    __syncthreads();
    short8 af[4], bfr[NC];
#pragma unroll
    for (int r = 0; r < 4; ++r)
      af[r] = *(const short8*)(As + (wr * 64 + r * 16 + l15) * 32 + l4 * 8);
#pragma unroll
    for (int c = 0; c < NC; ++c)
      bfr[c] = *(const short8*)(Bs + (wc * WN + c * 16 + l15) * 32 + l4 * 8);
#pragma unroll
    for (int r = 0; r < 4; ++r)
#pragma unroll
      for (int c = 0; c < NC; ++c)
        acc[r][c] = __builtin_amdgcn_mfma_f32_16x16x32_bf16(bfr[c], af[r], acc[r][c], 0, 0, 0);
    __syncthreads();
  }

  float bvj[NC][4];
#pragma unroll
  for (int c = 0; c < NC; ++c)
#pragma unroll
    for (int j = 0; j < 4; ++j)
      bvj[c][j] = bias[n0 + wc * WN + c * 16 + l4 * 4 + j];
  const float fac = (phase == 0 && z == 0)
      ? temp[(n0 + wc * WN) >> 6] * 0.18033688011112042f : 1.0f;

#pragma unroll
  for (int r = 0; r < 4; ++r) {
    const int mm = m0 + wr * 64 + r * 16 + l15;   // b*1024+s, lane-contiguous
    const int b = mm >> 10, s = mm & 1023;
#pragma unroll
    for (int c = 0; c < NC; ++c) {
      const int n = n0 + wc * WN + c * 16 + l4 * 4;  // 4 consecutive n per thread
      if (phase == 1) {
        float4v o;
#pragma unroll
        for (int j = 0; j < 4; ++j) o[j] = acc[r][c][j] + bvj[c][j];
        *(float4v*)(fo + (size_t)mm * 1024 + n) = o;
      } else if (z == 2) {
#pragma unroll
        for (int j = 0; j < 4; ++j)
          vT[((size_t)b * 1024 + n + j) * 1024 + s] = f2bf(acc[r][c][j] + bvj[c][j]);
      } else {
        unsigned lo = cvtpk((acc[r][c][0] + bvj[c][0]) * fac, (acc[r][c][1] + bvj[c][1]) * fac);
        unsigned hi = cvtpk((acc[r][c][2] + bvj[c][2]) * fac, (acc[r][c][3] + bvj[c][3]) * fac);
        unsigned o2[2] = {lo, hi};
        int hh = n >> 6, d = n & 63;
        u16* dst = (z == 0) ? qb : kb;
        *(unsigned long long*)(dst + ((((size_t)b * 16 + hh) * 1024 + s) * 64 + d)) =
            *(unsigned long long*)o2;
      }
    }
  }
}

// ---------- flash attention: 8 waves x 16q, KBLK=64, P fully in-register ----------
// S^T = mfma(K, Q): lane (l15,l4) holds q=l15, k = cb*16 + l4*4 + j.
// PV = mfma_16x16x32(Vfrag, Pfrag) with REMAPPED k-slots:
//   slot (l4*8 + cbl*4 + j) <-> actual k = kg*32 + cbl*16 + l4*4 + j
// so the B-operand (P) is exactly the lane's own cvtpk'd softmax output
// (zero cross-lane movement, no LDS round-trip), and the A-operand (V^T)
// is two 8-byte LDS reads per mfma with matching k-permutation.
__global__ __launch_bounds__(512, 4)
void attn_kernel(const u16* __restrict__ qb, const u16* __restrict__ kb, const u16* __restrict__ vT,
                 const u64* __restrict__ mbits, u16* __restrict__ oh) {
  __shared__ u16 Ks[2][64 * 64];   // 16 KiB [k][d]
  __shared__ u16 Vs[2][64 * 64];   // 16 KiB [d][k]
  const int tid = threadIdx.x, lane = tid & 63, w = tid >> 6;  // 8 waves
  const int l15 = lane & 15, l4 = lane >> 4;
  const int id = blockIdx.x;           // 512 blocks: xcd(8) x [bh-sub(8) x qx(8)]
  const int xcd = id & 7, sl = id >> 3;
  const int bh = xcd * 8 + (sl >> 3), qx = sl & 7;
  const int b = bh >> 4, h = bh & 15;
  const int q0 = qx * 128 + w * 16;
  const u16* qp = qb + ((size_t)bh * 1024 + q0) * 64;
  const u16* kp = kb + (size_t)bh * 1024 * 64;
  const u16* vp = vT + (size_t)bh * 64 * 1024;

  // staging: 512 threads x 1 chunk per buffer (16B), inverse-swizzled source
  const int sr = tid >> 3, sc = ((tid & 7) ^ (sr & 7)) * 8;
  const int swz8 = (l15 & 7) << 3;   // u16-index XOR for K reads (16B chunks)
  const int vswz = l15 & 7;          // chunk-index XOR for V reads

  short8 qf0 = *(const short8*)(qp + (size_t)l15 * 64 + l4 * 8);
  short8 qf1 = *(const short8*)(qp + (size_t)l15 * 64 + 32 + l4 * 8);

  float m = -1e30f, l = 0.f;
  f32x4 oacc[4] = {};   // O^T: d = db*16 + l4*4 + j, q = l15

  const u64* mb = mbits + (size_t)bh * 16 * 1024 + q0 + l15;
  u64 wcur = mb[0];

  // prologue: stage tile 0
  gload16(kp + (size_t)sr * 64 + sc, &Ks[0][tid * 8]);
  gload16(vp + (size_t)sr * 1024 + sc, &Vs[0][tid * 8]);

  for (int t = 0; t < 16; ++t) {
    const int buf = t & 1;
    __syncthreads();  // stage(t) drained (vmcnt(0) before barrier)

    if (t < 15) {  // stage t+1 (hidden under compute of t)
      const int k1 = (t + 1) * 64;
      gload16(kp + (size_t)(k1 + sr) * 64 + sc, &Ks[buf ^ 1][tid * 8]);
      gload16(vp + (size_t)sr * 1024 + k1 + sc, &Vs[buf ^ 1][tid * 8]);
    }
    u64 wnext = (t < 15) ? mb[(t + 1) * 1024] : 0ULL;

    // ---- S^T = K Q^T ----
    f32x4 s[4] = {};
    __builtin_amdgcn_s_setprio(1);
#pragma unroll
    for (int cb = 0; cb < 4; ++cb) {
      const u16* kr = &Ks[buf][(cb * 16 + l15) * 64];
      short8 kf0 = *(const short8*)(kr + ((l4 * 8) ^ swz8));
      short8 kf1 = *(const short8*)(kr + ((32 + l4 * 8) ^ swz8));
      s[cb] = __builtin_amdgcn_mfma_f32_16x16x32_bf16(kf0, qf0, s[cb], 0, 0, 0);
      s[cb] = __builtin_amdgcn_mfma_f32_16x16x32_bf16(kf1, qf1, s[cb], 0, 0, 0);
    }
    __builtin_amdgcn_s_setprio(0);

    // ---- online softmax, max over RAW scores, mask applied post-exp ----
    float mt = fmaxf(fmaxf(s[0][0], s[0][1]), fmaxf(s[0][2], s[0][3]));
#pragma unroll
    for (int cb = 1; cb < 4; ++cb)
      mt = fmaxf(mt, fmaxf(fmaxf(s[cb][0], s[cb][1]), fmaxf(s[cb][2], s[cb][3])));
    mt = fmaxf(mt, __shfl_xor(mt, 16));
    mt = fmaxf(mt, __shfl_xor(mt, 32));
    if (!__all(mt <= m + 8.f)) {   // T13 defer-max
      float mnew = fmaxf(m, mt);
      float al = exp2f(m - mnew);
      l *= al;
#pragma unroll
      for (int db = 0; db < 4; ++db) oacc[db] *= al;
      m = mnew;
    }
    unsigned hws[4] = {(unsigned)wcur, (unsigned)(wcur >> 16),
                       (unsigned)(wcur >> 32), (unsigned)(wcur >> 48)};
    float rs = 0.f;
#pragma unroll
    for (int cb = 0; cb < 4; ++cb) {
#pragma unroll
      for (int j = 0; j < 4; ++j) {
        float p = exp2f(s[cb][j] - m);
        p = ((hws[cb] >> (l4 * 4 + j)) & 1) ? p : 0.f;
        rs += p;
        s[cb][j] = p;
      }
    }
    rs += __shfl_xor(rs, 16);
    rs += __shfl_xor(rs, 32);
    l += rs;

    // ---- P -> bf16 in-register (these ARE the PV B-fragments) ----
    PackSS pb0, pb1;
    pb0.u[0] = cvtpk(s[0][0], s[0][1]); pb0.u[1] = cvtpk(s[0][2], s[0][3]);
    pb0.u[2] = cvtpk(s[1][0], s[1][1]); pb0.u[3] = cvtpk(s[1][2], s[1][3]);
    pb1.u[0] = cvtpk(s[2][0], s[2][1]); pb1.u[1] = cvtpk(s[2][2], s[2][3]);
    pb1.u[2] = cvtpk(s[3][0], s[3][1]); pb1.u[3] = cvtpk(s[3][2], s[3][3]);

    // ---- O^T += V^T P^T (k-slot-permuted mfma, V via 2x b64 reads) ----
    __builtin_amdgcn_s_setprio(1);
#pragma unroll
    for (int kg = 0; kg < 2; ++kg) {
#pragma unroll
      for (int db = 0; db < 4; ++db) {
        const u16* vrow = &Vs[buf][(db * 16 + l15) * 64];
        const int e0 = (((4 * kg + (l4 >> 1)) ^ vswz) << 3) + (l4 & 1) * 4;
        const int e1 = (((4 * kg + 2 + (l4 >> 1)) ^ vswz) << 3) + (l4 & 1) * 4;
        uint2v v0 = *(const uint2v*)(vrow + e0);
        uint2v v1 = *(const uint2v*)(vrow + e1);
        PackSS vf;
        vf.u[0] = v0[0]; vf.u[1] = v0[1]; vf.u[2] = v1[0]; vf.u[3] = v1[1];
        oacc[db] = __builtin_amdgcn_mfma_f32_16x16x32_bf16(
            vf.s, kg ? pb1.s : pb0.s, oacc[db], 0, 0, 0);
      }
    }
    __builtin_amdgcn_s_setprio(0);
    wcur = wnext;
  }

  // ---- finalize: O = O^T / l ----
  float rl = 1.f / l;
  u16* orow = oh + ((size_t)b * 1024 + q0 + l15) * 1024 + h * 64;
#pragma unroll
  for (int db = 0; db < 4; ++db) {
    unsigned a0 = cvtpk(oacc[db][0] * rl, oacc[db][1] * rl);
    unsigned a1 = cvtpk(oacc[db][2] * rl, oacc[db][3] * rl);
    unsigned oA[2] = {a0, a1};
    *(unsigned long long*)(orow + db * 16 + l4 * 4) = *(unsigned long long*)oA;
  }
}

// ---------- launch ----------
extern "C" void kernel_launch(void* const* d_in, const int* in_sizes, int n_in,
                              void* d_out, int out_size, void* d_ws, size_t ws_size,
                              hipStream_t stream) {
  const float* x = (const float*)d_in[0];
  const float* Wq = (const float*)d_in[1];
  const float* bq = (const float*)d_in[2];
  const float* Wk = (const float*)d_in[3];
  const float* bk = (const float*)d_in[4];
  const float* Wv = (const float*)d_in[5];
  const float* bv = (const float*)d_in[6];
  const float* Wo = (const float*)d_in[7];
  const float* bo = (const float*)d_in[8];
  const float* temp = (const float*)d_in[9];
  const void* mask = (const void*)d_in[10];

  char* ws = (char*)d_ws;
  u16* xb = (u16*)(ws + 256);                 // 8 MiB (x bf16; reused as oh later)
  u16* Wt = xb + (size_t)4 * 1024 * 1024;     // 8 MiB (Wq^T,Wk^T,Wv^T,Wo^T bf16)
  u16* qbuf = Wt + (size_t)4 * 1024 * 1024;   // 8 MiB [B,H,S,D] (q pre-scaled)
  u16* kbuf = qbuf + (size_t)4 * 1024 * 1024; // 8 MiB [B,H,S,D]
  u16* vTb = kbuf + (size_t)4 * 1024 * 1024;  // 8 MiB [B,H,D,S]
  u64* mbits = (u64*)(vTb + (size_t)4 * 1024 * 1024);  // 8 MiB bitmask
  u16* oh = xb;                               // alias: xb dead after QKV GEMM

  prep_kernel<<<12288, 256, 0, stream>>>(mask, mbits, x, xb, Wq, Wk, Wv, Wo, Wt);
  gemm_kernel<128><<<dim3(32, 8, 3), 256, 0, stream>>>(
      xb, Wt, Wt + 1024 * 1024, Wt + 2 * 1024 * 1024,
      bq, bk, bv, temp, qbuf, kbuf, vTb, nullptr, 0);
  attn_kernel<<<512, 512, 0, stream>>>(qbuf, kbuf, vTb, mbits, oh);
  gemm_kernel<64><<<dim3(32, 16, 1), 256, 0, stream>>>(
      oh, Wt + 3 * 1024 * 1024, nullptr, nullptr,
      bo, nullptr, nullptr, temp, nullptr, nullptr, nullptr, (float*)d_out, 1);
}